// Round 1
// baseline (2667.691 us; speedup 1.0000x reference)
//
#include <hip/hip_runtime.h>
#include <hip/hip_bf16.h>

#define BB 256
#define TT 512
#define XS 40
#define HS 128
#define GS 512  // 4*HS

enum { MODE_PROJ = 0, MODE_FLAT = 1, MODE_CONCAT = 2 };

__device__ __forceinline__ float fast_sigmoid(float x) {
    float e = __expf(-x);
    return __frcp_rn(1.0f + e);
}
__device__ __forceinline__ float fast_tanh(float x) {
    x = fminf(fmaxf(x, -15.0f), 15.0f);
    float e = __expf(2.0f * x);
    return (e - 1.0f) * __frcp_rn(e + 1.0f);
}

// Generic 64x64-tile fp32 GEMM: out[m, n0+n] = act(A_row(m) . W[n,:] + bias)
// MODE_PROJ: A rows remapped through (b, t0+tt) chunking, dual bias (bih+bhh)
// MODE_FLAT/CONCAT: m offset by t0 (row-chunk base); CONCAT: k<XS from A, else A2
template <int K, int NS, int MODE, bool RELU>
__global__ __launch_bounds__(256) void gemm_tile(
    const float* __restrict__ A, const float* __restrict__ A2,
    const float* __restrict__ W, const float* __restrict__ b1p,
    const float* __restrict__ b2p, float* __restrict__ out, int Tc, int t0) {
    constexpr int KP = K + 1;
    __shared__ float at[64 * KP];
    __shared__ float wt[64 * KP];
    const int tid = threadIdx.x;
    const int row0 = blockIdx.x * 64;
    const int n0 = blockIdx.y * 64;

    for (int idx = tid; idx < 64 * K; idx += 256) {
        int r = idx / K, c = idx - r * K;
        int m = row0 + r;
        float v;
        if (MODE == MODE_PROJ) {
            int b = m / Tc, tt = m - b * Tc;
            v = A[(size_t)(b * TT + t0 + tt) * K + c];
        } else if (MODE == MODE_FLAT) {
            v = A[(size_t)(m + t0) * K + c];
        } else {
            int mg = m + t0;
            v = (c < XS) ? A[(size_t)mg * XS + c] : A2[(size_t)mg * HS + (c - XS)];
        }
        at[r * KP + c] = v;
    }
    for (int idx = tid; idx < 64 * K; idx += 256) {
        int r = idx / K, c = idx - r * K;
        wt[r * KP + c] = W[(size_t)(n0 + r) * K + c];
    }
    __syncthreads();

    const int tx = tid & 15, ty = tid >> 4;
    float acc[4][4] = {};
#pragma unroll 2
    for (int k = 0; k < K; ++k) {
        float av[4], wv[4];
#pragma unroll
        for (int i = 0; i < 4; i++) av[i] = at[(ty * 4 + i) * KP + k];
#pragma unroll
        for (int j = 0; j < 4; j++) wv[j] = wt[(tx + 16 * j) * KP + k];
#pragma unroll
        for (int i = 0; i < 4; i++)
#pragma unroll
            for (int j = 0; j < 4; j++) acc[i][j] = fmaf(av[i], wv[j], acc[i][j]);
    }

#pragma unroll
    for (int i = 0; i < 4; i++) {
        int m = row0 + ty * 4 + i;
        size_t outbase;
        if (MODE == MODE_PROJ) outbase = (size_t)m * NS;
        else outbase = (size_t)(m + t0) * NS;
#pragma unroll
        for (int j = 0; j < 4; j++) {
            int n = n0 + tx + 16 * j;
            float v = acc[i][j] + b1p[n];
            if (MODE == MODE_PROJ) v += b2p[n];
            if (RELU) v = fmaxf(v, 0.0f);
            out[outbase + n] = v;
        }
    }
}

// One block per batch row; 512 threads, thread g owns gate g with Whh[g,:] in VGPRs.
// Iterates Tc steps reading precomputed xW chunk, updates h (LDS) and c (regs).
__global__ __launch_bounds__(512, 2) void lstm_rec(
    const float* __restrict__ Whh, const float* __restrict__ xW,
    const float* __restrict__ h0, const float* __restrict__ c0,
    float* __restrict__ hstate, float* __restrict__ cstate,
    float* __restrict__ y, int Tc, int t0) {
    const int b = blockIdx.x;
    const int g = threadIdx.x;  // 0..511
    __shared__ __align__(16) float h_sh[HS];
    __shared__ float act[GS];

    // per-thread recurrent weight row in registers
    float4 w4[32];
    const float4* wr = (const float4*)(Whh + (size_t)g * HS);
#pragma unroll
    for (int q = 0; q < 32; q++) w4[q] = wr[q];

    float c = 0.0f;
    if (g < HS) {
        float hv;
        if (t0 == 0) {
            hv = h0[(size_t)b * HS + g];
            c = c0[(size_t)b * HS + g];
        } else {
            hv = hstate[(size_t)b * HS + g];
            c = cstate[(size_t)b * HS + g];
        }
        h_sh[g] = hv;
    }
    __syncthreads();

    const float* xWrow = xW + (size_t)b * Tc * GS;
    float* yrow = y + ((size_t)b * TT + t0) * HS;
    const float4* h4 = (const float4*)h_sh;
    const int gate = g >> 7;  // 0=i 1=f 2=g 3=o (wave-uniform)

    for (int t = 0; t < Tc; ++t) {
        float a = xWrow[(size_t)t * GS + g];  // issue early; used after dot
        float s0 = 0.f, s1 = 0.f, s2 = 0.f, s3 = 0.f;
#pragma unroll
        for (int q = 0; q < 32; q++) {
            float4 hv = h4[q];
            s0 = fmaf(w4[q].x, hv.x, s0);
            s1 = fmaf(w4[q].y, hv.y, s1);
            s2 = fmaf(w4[q].z, hv.z, s2);
            s3 = fmaf(w4[q].w, hv.w, s3);
        }
        a += (s0 + s1) + (s2 + s3);
        float v = (gate == 2) ? fast_tanh(a) : fast_sigmoid(a);
        act[g] = v;
        __syncthreads();
        if (g < HS) {
            float iv = act[g], fv = act[HS + g], gv = act[2 * HS + g], ov = act[3 * HS + g];
            c = fmaf(fv, c, iv * gv);
            float hv = ov * fast_tanh(c);
            h_sh[g] = hv;
            yrow[(size_t)t * HS + g] = hv;
        }
        __syncthreads();
    }
    if (g < HS) {
        hstate[(size_t)b * HS + g] = h_sh[g];
        cstate[(size_t)b * HS + g] = c;
    }
}

// out[row] = dot(z2[row,:], W3[0,:]) + b3 — one wave per row
__global__ __launch_bounds__(256) void head_dot(
    const float* __restrict__ z2, const float* __restrict__ W3,
    const float* __restrict__ b3, float* __restrict__ out) {
    const int wave = threadIdx.x >> 6, lane = threadIdx.x & 63;
    const int row = blockIdx.x * 4 + wave;
    const float* zr = z2 + (size_t)row * HS;
    float v = zr[lane] * W3[lane] + zr[64 + lane] * W3[64 + lane];
#pragma unroll
    for (int m = 32; m >= 1; m >>= 1) v += __shfl_xor(v, m, 64);
    if (lane == 0) out[row] = v + b3[0];
}

extern "C" void kernel_launch(void* const* d_in, const int* in_sizes, int n_in,
                              void* d_out, int out_size, void* d_ws, size_t ws_size,
                              hipStream_t stream) {
    const float* x = (const float*)d_in[0];
    const float* h0 = (const float*)d_in[1];
    const float* c0 = (const float*)d_in[2];
    const float* Wih[3] = {(const float*)d_in[3], (const float*)d_in[7], (const float*)d_in[11]};
    const float* Whh[3] = {(const float*)d_in[4], (const float*)d_in[8], (const float*)d_in[12]};
    const float* bih[3] = {(const float*)d_in[5], (const float*)d_in[9], (const float*)d_in[13]};
    const float* bhh[3] = {(const float*)d_in[6], (const float*)d_in[10], (const float*)d_in[14]};
    const float* W1 = (const float*)d_in[15];
    const float* b1 = (const float*)d_in[16];
    const float* W2 = (const float*)d_in[17];
    const float* b2 = (const float*)d_in[18];
    const float* W3 = (const float*)d_in[19];
    const float* b3 = (const float*)d_in[20];
    float* outp = (float*)d_out;

    // workspace layout: y[B,T,H] | xW[B,Tc,4H] | hstate[B,H] | cstate[B,H]
    int Tc = TT;
    while (Tc > 8) {
        size_t need = ((size_t)BB * TT * HS + (size_t)BB * Tc * GS + 2 * (size_t)BB * HS) * 4;
        if (need <= ws_size) break;
        Tc >>= 1;
    }
    float* yb = (float*)d_ws;
    float* xw = yb + (size_t)BB * TT * HS;
    float* hs = xw + (size_t)BB * Tc * GS;
    float* cs = hs + (size_t)BB * HS;

    for (int l = 0; l < 3; ++l) {
        for (int t0 = 0; t0 < TT; t0 += Tc) {
            dim3 gp(BB * Tc / 64, GS / 64);
            if (l == 0)
                gemm_tile<XS, GS, MODE_PROJ, false><<<gp, 256, 0, stream>>>(
                    x, nullptr, Wih[0], bih[0], bhh[0], xw, Tc, t0);
            else
                gemm_tile<HS, GS, MODE_PROJ, false><<<gp, 256, 0, stream>>>(
                    yb, nullptr, Wih[l], bih[l], bhh[l], xw, Tc, t0);
            lstm_rec<<<BB, 512, 0, stream>>>(Whh[l], xw,
                                             h0 + (size_t)l * BB * HS, c0 + (size_t)l * BB * HS,
                                             hs, cs, yb, Tc, t0);
        }
    }

    // MLP head, row-chunked so z1 fits in the xw buffer
    const int totalRows = BB * TT;
    int Rc = BB * Tc * (GS / HS);  // rows of z1 (128 wide) that fit in xw
    if (Rc > totalRows) Rc = totalRows;
    for (int r0 = 0; r0 < totalRows; r0 += Rc) {
        dim3 gm(Rc / 64, HS / 64);
        gemm_tile<XS + HS, HS, MODE_CONCAT, true><<<gm, 256, 0, stream>>>(
            x, yb, W1, b1, nullptr, xw, 0, r0);
        gemm_tile<HS, HS, MODE_FLAT, true><<<gm, 256, 0, stream>>>(
            xw, nullptr, W2, b2, nullptr, yb, 0, r0);
    }
    head_dot<<<totalRows / 4, 256, 0, stream>>>(yb, W3, b3, outp);
}